// Round 1
// baseline (6353.749 us; speedup 1.0000x reference)
//
#include <hip/hip_runtime.h>

#define CH 64

// One wave (64 lanes) per triangle; lane = output channel.
// Gathers x = A[ia] + B[ib] (64 floats), computes y = x @ W + b via
// shfl-broadcast of x[k] against a per-lane register copy of W's column,
// then atomically adds y into dst[id].
__global__ __launch_bounds__(256) void tri_pass_kernel(
    const float* __restrict__ A, const float* __restrict__ B,
    const float* __restrict__ W, const float* __restrict__ bvec,
    const int* __restrict__ idx_dst, const int* __restrict__ idx_a,
    const int* __restrict__ idx_b, int T, float* __restrict__ dst)
{
    const int lane = threadIdx.x & 63;

    // Register copy of W column `lane`: wreg[k] = W[k][lane]. Fully static
    // indexing below keeps this in VGPRs (64 regs).
    float wreg[CH];
    #pragma unroll
    for (int k = 0; k < CH; ++k) wreg[k] = W[k * CH + lane];
    const float bias = bvec[lane];

    const int wave  = blockIdx.x * (blockDim.x >> 6) + (threadIdx.x >> 6);
    const int nwave = gridDim.x * (blockDim.x >> 6);

    for (int t = wave; t < T; t += nwave) {
        const int ia = idx_a[t];
        const int ib = idx_b[t];
        const int id = idx_dst[t];
        const float x = A[(long)ia * CH + lane] + B[(long)ib * CH + lane];
        float y = bias;
        #pragma unroll
        for (int k = 0; k < CH; ++k)
            y = fmaf(__shfl(x, k), wreg[k], y);
        atomicAdd(&dst[(long)id * CH + lane], y);
    }
}

// Finalize: inout[r] = mlp( inout[r] + m[r] + m[inv[r]] )
// mlp(x) = relu(x @ W1 + b1) @ W2 + b2, all 64-dim. W1 in registers,
// W2 in LDS. In-place row write (each row read+written by its own wave).
__global__ __launch_bounds__(256) void mlp_finalize_kernel(
    const float* __restrict__ m, const int* __restrict__ inv,
    const float* __restrict__ W1, const float* __restrict__ b1,
    const float* __restrict__ W2, const float* __restrict__ b2,
    int N, float* __restrict__ inout)
{
    __shared__ float W2l[CH * CH];
    for (int i = threadIdx.x; i < CH * CH; i += blockDim.x) W2l[i] = W2[i];

    const int lane = threadIdx.x & 63;
    float w1reg[CH];
    #pragma unroll
    for (int k = 0; k < CH; ++k) w1reg[k] = W1[k * CH + lane];
    const float bb1 = b1[lane];
    const float bb2 = b2[lane];
    __syncthreads();

    const int wave  = blockIdx.x * (blockDim.x >> 6) + (threadIdx.x >> 6);
    const int nwave = gridDim.x * (blockDim.x >> 6);

    for (int r = wave; r < N; r += nwave) {
        const int iv = inv[r];
        const float x = inout[(long)r * CH + lane]
                      + m[(long)r * CH + lane]
                      + m[(long)iv * CH + lane];
        float h = bb1;
        #pragma unroll
        for (int k = 0; k < CH; ++k)
            h = fmaf(__shfl(x, k), w1reg[k], h);
        h = fmaxf(h, 0.0f);
        float o = bb2;
        #pragma unroll
        for (int k = 0; k < CH; ++k)
            o = fmaf(__shfl(h, k), W2l[k * CH + lane], o);
        inout[(long)r * CH + lane] = o;
    }
}

extern "C" void kernel_launch(void* const* d_in, const int* in_sizes, int n_in,
                              void* d_out, int out_size, void* d_ws, size_t ws_size,
                              hipStream_t stream)
{
    const float* ea  = (const float*)d_in[0];
    const float* ea2 = (const float*)d_in[1];
    const float* Wp  = (const float*)d_in[2];   // (6,64,64)
    const float* bp  = (const float*)d_in[3];   // (6,64)
    const float* W1a = (const float*)d_in[4];
    const float* b1a = (const float*)d_in[5];
    const float* W2a = (const float*)d_in[6];
    const float* b2a = (const float*)d_in[7];
    const float* W1b = (const float*)d_in[8];
    const float* b1b = (const float*)d_in[9];
    const float* W2b = (const float*)d_in[10];
    const float* b2b = (const float*)d_in[11];
    const int* t111 = (const int*)d_in[12];     // [3,T]: ij, ik, kj
    const int* t112 = (const int*)d_in[13];
    const int* t122 = (const int*)d_in[14];
    const int* t222 = (const int*)d_in[15];
    const int* inv1 = (const int*)d_in[16];
    const int* inv2 = (const int*)d_in[17];

    const int E  = in_sizes[0] / CH;
    const int E2 = in_sizes[1] / CH;
    const int T  = in_sizes[12] / 3;

    float* out1 = (float*)d_out;                  // acc1 then new edge_attr
    float* out2 = out1 + (size_t)E * CH;          // acc2 then new edge_attr2
    float* m112 = (float*)d_ws;                   // E x 64
    float* m212 = m112 + (size_t)E * CH;          // E2 x 64

    const dim3 blk(256);
    const int NB = 4096;

    // ---- Phase 1 ----
    hipMemcpyAsync(out1, ea, (size_t)E * CH * sizeof(float),
                   hipMemcpyDeviceToDevice, stream);
    hipMemsetAsync(m112, 0, (size_t)E * CH * sizeof(float), stream);

    // m111: proj0(ea[ik]+ea[kj]) scatter ij  -> acc1
    tri_pass_kernel<<<NB, blk, 0, stream>>>(ea, ea, Wp + 0 * CH * CH, bp + 0 * CH,
                                            t111 + 0, t111 + T, t111 + 2 * T, T, out1);
    // m112: proj1(ea[ik]+ea2[kj]) scatter ij -> m112 (added twice in finalize)
    tri_pass_kernel<<<NB, blk, 0, stream>>>(ea, ea2, Wp + 1 * CH * CH, bp + 1 * CH,
                                            t112 + 0, t112 + T, t112 + 2 * T, T, m112);
    // m122: proj2(ea2[ik]+ea2[kj]) scatter ij -> acc1
    tri_pass_kernel<<<NB, blk, 0, stream>>>(ea2, ea2, Wp + 2 * CH * CH, bp + 2 * CH,
                                            t122 + 0, t122 + T, t122 + 2 * T, T, out1);
    // edge_attr' = mlp_a(acc1 + m112 + m112[inv1])
    mlp_finalize_kernel<<<NB, blk, 0, stream>>>(m112, inv1, W1a, b1a, W2a, b2a, E, out1);

    // ---- Phase 2 (uses NEW edge_attr = out1) ----
    hipMemcpyAsync(out2, ea2, (size_t)E2 * CH * sizeof(float),
                   hipMemcpyDeviceToDevice, stream);
    hipMemsetAsync(m212, 0, (size_t)E2 * CH * sizeof(float), stream);

    // m211: proj3(ea'[ij112]+ea'[ik112]) scatter kj112 -> acc2
    tri_pass_kernel<<<NB, blk, 0, stream>>>(out1, out1, Wp + 3 * CH * CH, bp + 3 * CH,
                                            t112 + 2 * T, t112 + 0, t112 + T, T, out2);
    // m212: proj4(ea'[ij122]+ea2[kj122]) scatter ik122 -> m212 (added twice in finalize)
    tri_pass_kernel<<<NB, blk, 0, stream>>>(out1, ea2, Wp + 4 * CH * CH, bp + 4 * CH,
                                            t122 + T, t122 + 0, t122 + 2 * T, T, m212);
    // m222: proj5(ea2[ik222]+ea2[kj222]) scatter ij222 -> acc2
    tri_pass_kernel<<<NB, blk, 0, stream>>>(ea2, ea2, Wp + 5 * CH * CH, bp + 5 * CH,
                                            t222 + 0, t222 + T, t222 + 2 * T, T, out2);
    // edge_attr2' = mlp_b(acc2 + m212 + m212[inv2])
    mlp_finalize_kernel<<<NB, blk, 0, stream>>>(m212, inv2, W1b, b1b, W2b, b2b, E2, out2);
}

// Round 2
// 3600.517 us; speedup vs baseline: 1.7647x; 1.7647x over previous
//
#include <hip/hip_runtime.h>

#define CH 64

// Scatter raw gathered sums: S[dst] += A[ia] + B[ib] (64 ch, fp32 atomics),
// cnt[dst] += 1. No per-triangle matmul (deferred via linearity).
__global__ __launch_bounds__(256) void scatter_sum_kernel(
    const float* __restrict__ A, const float* __restrict__ B,
    const int* __restrict__ idx_dst, const int* __restrict__ idx_a,
    const int* __restrict__ idx_b, int T,
    float* __restrict__ S, int* __restrict__ cnt)
{
    const int lane  = threadIdx.x & 63;
    const int wave  = blockIdx.x * (blockDim.x >> 6) + (threadIdx.x >> 6);
    const int nwave = gridDim.x * (blockDim.x >> 6);
    for (int t = wave; t < T; t += nwave) {
        const int ts = __builtin_amdgcn_readfirstlane(t);  // force SGPR -> s_load idx
        const int ia = idx_a[ts];
        const int ib = idx_b[ts];
        const int id = idx_dst[ts];
        const float x = A[(size_t)ia * CH + lane] + B[(size_t)ib * CH + lane];
        atomicAdd(&S[(size_t)id * CH + lane], x);
        if (lane == 0) atomicAdd(&cnt[id], 1);
    }
}

// out[r] += (S[r] (+ S[inv[r]])) @ W + (cnt[r] (+ cnt[inv[r]])) * b
// Thread-per-row; row in VGPRs (static idx); W/b at lane-uniform addresses
// (scalarized to s_load); 64 independent accumulators -> full VALU ILP.
template<bool WITH_INV>
__global__ __launch_bounds__(256) void matvec_acc_kernel(
    const float* __restrict__ S, const int* __restrict__ cnt,
    const int* __restrict__ inv, const float* __restrict__ W,
    const float* __restrict__ bv, int N, float* __restrict__ out)
{
    const int r0 = blockIdx.x * blockDim.x + threadIdx.x;
    const int r = r0 < N ? r0 : N - 1;   // clamp addresses; guard only stores
    const bool valid = r0 < N;

    float x[CH];
    {
        const float4* s4 = reinterpret_cast<const float4*>(S + (size_t)r * CH);
        #pragma unroll
        for (int k = 0; k < CH / 4; ++k) {
            const float4 v = s4[k];
            x[4*k+0] = v.x; x[4*k+1] = v.y; x[4*k+2] = v.z; x[4*k+3] = v.w;
        }
    }
    float cf = (float)cnt[r];
    if (WITH_INV) {
        const int iv = inv[r];
        const float4* s4 = reinterpret_cast<const float4*>(S + (size_t)iv * CH);
        #pragma unroll
        for (int k = 0; k < CH / 4; ++k) {
            const float4 v = s4[k];
            x[4*k+0] += v.x; x[4*k+1] += v.y; x[4*k+2] += v.z; x[4*k+3] += v.w;
        }
        cf += (float)cnt[iv];
    }

    float* orow = out + (size_t)r * CH;
    for (int j0 = 0; j0 < CH; j0 += 8) {   // dynamic loop keeps code small
        float acc[8];
        {
            const float4 o0 = *reinterpret_cast<const float4*>(orow + j0);
            const float4 o1 = *reinterpret_cast<const float4*>(orow + j0 + 4);
            const float4 b0 = *reinterpret_cast<const float4*>(bv + j0);
            const float4 b1 = *reinterpret_cast<const float4*>(bv + j0 + 4);
            acc[0] = fmaf(cf, b0.x, o0.x); acc[1] = fmaf(cf, b0.y, o0.y);
            acc[2] = fmaf(cf, b0.z, o0.z); acc[3] = fmaf(cf, b0.w, o0.w);
            acc[4] = fmaf(cf, b1.x, o1.x); acc[5] = fmaf(cf, b1.y, o1.y);
            acc[6] = fmaf(cf, b1.z, o1.z); acc[7] = fmaf(cf, b1.w, o1.w);
        }
        #pragma unroll
        for (int k = 0; k < CH; ++k) {
            const float* wr = W + k * CH + j0;   // lane-uniform -> s_load
            #pragma unroll
            for (int jj = 0; jj < 8; ++jj)
                acc[jj] = fmaf(x[k], wr[jj], acc[jj]);
        }
        if (valid) {
            *reinterpret_cast<float4*>(orow + j0)     = make_float4(acc[0], acc[1], acc[2], acc[3]);
            *reinterpret_cast<float4*>(orow + j0 + 4) = make_float4(acc[4], acc[5], acc[6], acc[7]);
        }
    }
}

// In-place MLP: inout[r] = relu(inout[r] @ W1 + b1) @ W2 + b2.
// Thread-per-row; hidden layer staged in thread-private LDS column
// (no barriers needed), keeping all register indexing static.
__global__ __launch_bounds__(128) void mlp_kernel(
    const float* __restrict__ W1, const float* __restrict__ b1,
    const float* __restrict__ W2, const float* __restrict__ b2,
    int N, float* __restrict__ inout)
{
    __shared__ float hl[CH * 128];   // 32 KiB: [j][tid]
    const int tid = threadIdx.x;
    const int r0 = blockIdx.x * blockDim.x + tid;
    const int r = r0 < N ? r0 : N - 1;
    const bool valid = r0 < N;

    float* row = inout + (size_t)r * CH;
    float x[CH];
    {
        const float4* s4 = reinterpret_cast<const float4*>(row);
        #pragma unroll
        for (int k = 0; k < CH / 4; ++k) {
            const float4 v = s4[k];
            x[4*k+0] = v.x; x[4*k+1] = v.y; x[4*k+2] = v.z; x[4*k+3] = v.w;
        }
    }

    // layer 1 -> LDS
    for (int j0 = 0; j0 < CH; j0 += 8) {
        float acc[8];
        {
            const float4 b0 = *reinterpret_cast<const float4*>(b1 + j0);
            const float4 b1v = *reinterpret_cast<const float4*>(b1 + j0 + 4);
            acc[0] = b0.x; acc[1] = b0.y; acc[2] = b0.z; acc[3] = b0.w;
            acc[4] = b1v.x; acc[5] = b1v.y; acc[6] = b1v.z; acc[7] = b1v.w;
        }
        #pragma unroll
        for (int k = 0; k < CH; ++k) {
            const float* wr = W1 + k * CH + j0;
            #pragma unroll
            for (int jj = 0; jj < 8; ++jj)
                acc[jj] = fmaf(x[k], wr[jj], acc[jj]);
        }
        #pragma unroll
        for (int jj = 0; jj < 8; ++jj)
            hl[(j0 + jj) * 128 + tid] = fmaxf(acc[jj], 0.0f);
    }

    // layer 2
    float h[CH];
    #pragma unroll
    for (int k = 0; k < CH; ++k) h[k] = hl[k * 128 + tid];

    for (int j0 = 0; j0 < CH; j0 += 8) {
        float acc[8];
        {
            const float4 b0 = *reinterpret_cast<const float4*>(b2 + j0);
            const float4 b1v = *reinterpret_cast<const float4*>(b2 + j0 + 4);
            acc[0] = b0.x; acc[1] = b0.y; acc[2] = b0.z; acc[3] = b0.w;
            acc[4] = b1v.x; acc[5] = b1v.y; acc[6] = b1v.z; acc[7] = b1v.w;
        }
        #pragma unroll
        for (int k = 0; k < CH; ++k) {
            const float* wr = W2 + k * CH + j0;
            #pragma unroll
            for (int jj = 0; jj < 8; ++jj)
                acc[jj] = fmaf(h[k], wr[jj], acc[jj]);
        }
        if (valid) {
            *reinterpret_cast<float4*>(row + j0)     = make_float4(acc[0], acc[1], acc[2], acc[3]);
            *reinterpret_cast<float4*>(row + j0 + 4) = make_float4(acc[4], acc[5], acc[6], acc[7]);
        }
    }
}

extern "C" void kernel_launch(void* const* d_in, const int* in_sizes, int n_in,
                              void* d_out, int out_size, void* d_ws, size_t ws_size,
                              hipStream_t stream)
{
    const float* ea  = (const float*)d_in[0];
    const float* ea2 = (const float*)d_in[1];
    const float* Wp  = (const float*)d_in[2];   // (6,64,64)
    const float* bp  = (const float*)d_in[3];   // (6,64)
    const float* W1a = (const float*)d_in[4];
    const float* b1a = (const float*)d_in[5];
    const float* W2a = (const float*)d_in[6];
    const float* b2a = (const float*)d_in[7];
    const float* W1b = (const float*)d_in[8];
    const float* b1b = (const float*)d_in[9];
    const float* W2b = (const float*)d_in[10];
    const float* b2b = (const float*)d_in[11];
    const int* t111 = (const int*)d_in[12];     // [3,T]: ij, ik, kj
    const int* t112 = (const int*)d_in[13];
    const int* t122 = (const int*)d_in[14];
    const int* t222 = (const int*)d_in[15];
    const int* inv1 = (const int*)d_in[16];
    const int* inv2 = (const int*)d_in[17];

    const int E    = in_sizes[0] / CH;
    const int E2   = in_sizes[1] / CH;
    const int T111 = in_sizes[12] / 3;
    const int T112 = in_sizes[13] / 3;
    const int T122 = in_sizes[14] / 3;
    const int T222 = in_sizes[15] / 3;

    float* out1 = (float*)d_out;                 // E  x 64 (acc then result)
    float* out2 = out1 + (size_t)E * CH;         // E2 x 64

    const int Emax = E > E2 ? E : E2;
    float* S   = (float*)d_ws;                   // Emax x 64
    int*   cnt = (int*)((char*)d_ws + (size_t)Emax * CH * sizeof(float));

    const dim3 blk256(256), blk128(128);
    const int SCAT_NB = 4096;
    const size_t S1_bytes = (size_t)E * CH * sizeof(float);
    const size_t S2_bytes = (size_t)E2 * CH * sizeof(float);

    // ================= Phase 1 (edges1) =================
    hipMemcpyAsync(out1, ea, S1_bytes, hipMemcpyDeviceToDevice, stream);

    // m111: raw sums of ea[ik]+ea[kj] seg by ij
    hipMemsetAsync(S, 0, S1_bytes, stream);
    hipMemsetAsync(cnt, 0, (size_t)E * sizeof(int), stream);
    scatter_sum_kernel<<<SCAT_NB, blk256, 0, stream>>>(
        ea, ea, t111 + 0, t111 + T111, t111 + 2 * T111, T111, S, cnt);
    matvec_acc_kernel<false><<<(E + 255) / 256, blk256, 0, stream>>>(
        S, cnt, nullptr, Wp + 0 * CH * CH, bp + 0 * CH, E, out1);

    // m122: ea2[ik]+ea2[kj] seg by ij
    hipMemsetAsync(S, 0, S1_bytes, stream);
    hipMemsetAsync(cnt, 0, (size_t)E * sizeof(int), stream);
    scatter_sum_kernel<<<SCAT_NB, blk256, 0, stream>>>(
        ea2, ea2, t122 + 0, t122 + T122, t122 + 2 * T122, T122, S, cnt);
    matvec_acc_kernel<false><<<(E + 255) / 256, blk256, 0, stream>>>(
        S, cnt, nullptr, Wp + 2 * CH * CH, bp + 2 * CH, E, out1);

    // m112 (+ m112[inv1]): ea[ik]+ea2[kj] seg by ij
    hipMemsetAsync(S, 0, S1_bytes, stream);
    hipMemsetAsync(cnt, 0, (size_t)E * sizeof(int), stream);
    scatter_sum_kernel<<<SCAT_NB, blk256, 0, stream>>>(
        ea, ea2, t112 + 0, t112 + T112, t112 + 2 * T112, T112, S, cnt);
    matvec_acc_kernel<true><<<(E + 255) / 256, blk256, 0, stream>>>(
        S, cnt, inv1, Wp + 1 * CH * CH, bp + 1 * CH, E, out1);

    mlp_kernel<<<(E + 127) / 128, blk128, 0, stream>>>(W1a, b1a, W2a, b2a, E, out1);

    // ================= Phase 2 (edges2) =================
    hipMemcpyAsync(out2, ea2, S2_bytes, hipMemcpyDeviceToDevice, stream);

    // m211: ea'[ij112]+ea'[ik112] seg by kj112
    hipMemsetAsync(S, 0, S2_bytes, stream);
    hipMemsetAsync(cnt, 0, (size_t)E2 * sizeof(int), stream);
    scatter_sum_kernel<<<SCAT_NB, blk256, 0, stream>>>(
        out1, out1, t112 + 2 * T112, t112 + 0, t112 + T112, T112, S, cnt);
    matvec_acc_kernel<false><<<(E2 + 255) / 256, blk256, 0, stream>>>(
        S, cnt, nullptr, Wp + 3 * CH * CH, bp + 3 * CH, E2, out2);

    // m222: ea2[ik]+ea2[kj] seg by ij
    hipMemsetAsync(S, 0, S2_bytes, stream);
    hipMemsetAsync(cnt, 0, (size_t)E2 * sizeof(int), stream);
    scatter_sum_kernel<<<SCAT_NB, blk256, 0, stream>>>(
        ea2, ea2, t222 + 0, t222 + T222, t222 + 2 * T222, T222, S, cnt);
    matvec_acc_kernel<false><<<(E2 + 255) / 256, blk256, 0, stream>>>(
        S, cnt, nullptr, Wp + 5 * CH * CH, bp + 5 * CH, E2, out2);

    // m212 (+ m212[inv2]): ea'[ij122]+ea2[kj122] seg by ik122
    hipMemsetAsync(S, 0, S2_bytes, stream);
    hipMemsetAsync(cnt, 0, (size_t)E2 * sizeof(int), stream);
    scatter_sum_kernel<<<SCAT_NB, blk256, 0, stream>>>(
        out1, ea2, t122 + T122, t122 + 0, t122 + 2 * T122, T122, S, cnt);
    matvec_acc_kernel<true><<<(E2 + 255) / 256, blk256, 0, stream>>>(
        S, cnt, inv2, Wp + 4 * CH * CH, bp + 4 * CH, E2, out2);

    mlp_kernel<<<(E2 + 127) / 128, blk128, 0, stream>>>(W1b, b1b, W2b, b2b, E2, out2);
}

// Round 3
// 2421.769 us; speedup vs baseline: 2.6236x; 1.4867x over previous
//
#include <hip/hip_runtime.h>

#define CH 64

typedef unsigned int uint;

// ---------- bf16 helpers ----------
__device__ __forceinline__ float bf_lo(uint u) {
    union { uint a; float f; } c; c.a = u << 16; return c.f;
}
__device__ __forceinline__ float bf_hi(uint u) {
    union { uint a; float f; } c; c.a = u & 0xffff0000u; return c.f;
}
__device__ __forceinline__ uint pack_bf162(float lo, float hi) {
    uint a = __float_as_uint(lo), b = __float_as_uint(hi);
    a = (a + 0x7fffu + ((a >> 16) & 1u)) >> 16;
    b = (b + 0x7fffu + ((b >> 16) & 1u)) >> 16;
    return a | (b << 16);
}
// HW packed bf16 atomic add (gfx942+/gfx950): one 4B atomic adds 2 channels.
__device__ __forceinline__ void atom_pk_add_bf16(uint* addr, float lo, float hi) {
    uint v = pack_bf162(lo, hi);
    asm volatile("global_atomic_pk_add_bf16 %0, %1, off"
                 :: "v"(addr), "v"(v) : "memory");
}

// ---------- scatter: S[dst] += bf16(A[ia]+B[ib]), cnt[dst] += 1 ----------
// 32 lanes per triangle (2 channels/lane), 2 triangles per wave.
__global__ __launch_bounds__(256) void scatter_sum_bf16(
    const float* __restrict__ A, const float* __restrict__ B,
    const int* __restrict__ idx_dst, const int* __restrict__ idx_a,
    const int* __restrict__ idx_b, int T,
    uint* __restrict__ S, float* __restrict__ cnt)
{
    const int l32  = threadIdx.x & 31;
    const int half = (threadIdx.x >> 5) & 1;
    const int wave  = blockIdx.x * (blockDim.x >> 6) + (threadIdx.x >> 6);
    const int nwave = gridDim.x * (blockDim.x >> 6);

    for (int w = wave; 2 * w < T; w += nwave) {
        const int t = 2 * w + half;
        if (t < T) {
            const int ia = idx_a[t];
            const int ib = idx_b[t];
            const int id = idx_dst[t];
            const float2 va = *(const float2*)(A + (size_t)ia * CH + l32 * 2);
            const float2 vb = *(const float2*)(B + (size_t)ib * CH + l32 * 2);
            atom_pk_add_bf16(S + (size_t)id * 32 + l32, va.x + vb.x, va.y + vb.y);
            if (l32 == 0) atomicAdd(&cnt[id], 1.0f);
        }
    }
}

// ---------- one matvec stage: z += x @ W, x = unpack(Srow[,+Srow2]) ----------
// zc = &zbuf[0] + tid, column stride 128 floats. No cross-thread sharing.
template<bool TWO>
__device__ __forceinline__ void mv_stage(const uint* __restrict__ Srow,
                                         const uint* __restrict__ Srow2,
                                         const float* __restrict__ W,
                                         float* zc)
{
    float x[CH];
    #pragma unroll
    for (int q = 0; q < 8; ++q) {
        const uint4 u = *(const uint4*)(Srow + q * 4);
        x[q*8+0] = bf_lo(u.x); x[q*8+1] = bf_hi(u.x);
        x[q*8+2] = bf_lo(u.y); x[q*8+3] = bf_hi(u.y);
        x[q*8+4] = bf_lo(u.z); x[q*8+5] = bf_hi(u.z);
        x[q*8+6] = bf_lo(u.w); x[q*8+7] = bf_hi(u.w);
    }
    if (TWO) {
        #pragma unroll
        for (int q = 0; q < 8; ++q) {
            const uint4 u = *(const uint4*)(Srow2 + q * 4);
            x[q*8+0] += bf_lo(u.x); x[q*8+1] += bf_hi(u.x);
            x[q*8+2] += bf_lo(u.y); x[q*8+3] += bf_hi(u.y);
            x[q*8+4] += bf_lo(u.z); x[q*8+5] += bf_hi(u.z);
            x[q*8+6] += bf_lo(u.w); x[q*8+7] += bf_hi(u.w);
        }
    }
    #pragma unroll 1
    for (int j0 = 0; j0 < CH; j0 += 8) {
        float acc[8];
        #pragma unroll
        for (int jj = 0; jj < 8; ++jj) acc[jj] = zc[(j0 + jj) * 128];
        #pragma unroll
        for (int k = 0; k < CH; ++k) {
            const float* wr = W + k * CH + j0;   // uniform -> s_load
            #pragma unroll
            for (int jj = 0; jj < 8; ++jj)
                acc[jj] = fmaf(x[k], wr[jj], acc[jj]);
        }
        #pragma unroll
        for (int jj = 0; jj < 8; ++jj) zc[(j0 + jj) * 128] = acc[jj];
    }
}

// ---------- fused finalize:
// out[r] = mlp( base[r] + SA@WA + cA*bA + SB@WB + cB*bB
//               + (SC[r]+SC[inv])@WC + (cC[r]+cC[inv])*bC ) ----------
__global__ __launch_bounds__(128) void fused_finalize(
    const float* __restrict__ base,
    const uint* __restrict__ SA, const float* __restrict__ cA,
    const float* __restrict__ WA, const float* __restrict__ bA,
    const uint* __restrict__ SB, const float* __restrict__ cB,
    const float* __restrict__ WB, const float* __restrict__ bB,
    const uint* __restrict__ SC, const float* __restrict__ cC,
    const float* __restrict__ WC, const float* __restrict__ bC,
    const int* __restrict__ inv,
    const float* __restrict__ W1, const float* __restrict__ b1,
    const float* __restrict__ W2, const float* __restrict__ b2,
    int N, float* __restrict__ out)
{
    __shared__ float zbuf[CH * 128];   // 32 KiB: [k][tid], thread-private column
    const int tid = threadIdx.x;
    const int r0 = blockIdx.x * 128 + tid;
    const int r = r0 < N ? r0 : N - 1;
    const bool valid = r0 < N;
    float* zc = zbuf + tid;

    const int iv = inv[r];
    const float cfA = cA[r];
    const float cfB = cB[r];
    const float cfC = cC[r] + cC[iv];

    // init: z = base + cfA*bA + cfB*bB + cfC*bC
    const float* brow = base + (size_t)r * CH;
    #pragma unroll 1
    for (int j0 = 0; j0 < CH; j0 += 8) {
        const float4 e0 = *(const float4*)(brow + j0);
        const float4 e1 = *(const float4*)(brow + j0 + 4);
        const float4 a0 = *(const float4*)(bA + j0);
        const float4 a1 = *(const float4*)(bA + j0 + 4);
        const float4 p0 = *(const float4*)(bB + j0);
        const float4 p1 = *(const float4*)(bB + j0 + 4);
        const float4 q0 = *(const float4*)(bC + j0);
        const float4 q1 = *(const float4*)(bC + j0 + 4);
        zc[(j0+0)*128] = e0.x + cfA*a0.x + cfB*p0.x + cfC*q0.x;
        zc[(j0+1)*128] = e0.y + cfA*a0.y + cfB*p0.y + cfC*q0.y;
        zc[(j0+2)*128] = e0.z + cfA*a0.z + cfB*p0.z + cfC*q0.z;
        zc[(j0+3)*128] = e0.w + cfA*a0.w + cfB*p0.w + cfC*q0.w;
        zc[(j0+4)*128] = e1.x + cfA*a1.x + cfB*p1.x + cfC*q1.x;
        zc[(j0+5)*128] = e1.y + cfA*a1.y + cfB*p1.y + cfC*q1.y;
        zc[(j0+6)*128] = e1.z + cfA*a1.z + cfB*p1.z + cfC*q1.z;
        zc[(j0+7)*128] = e1.w + cfA*a1.w + cfB*p1.w + cfC*q1.w;
    }

    mv_stage<false>(SA + (size_t)r * 32, nullptr,            WA, zc);
    mv_stage<false>(SB + (size_t)r * 32, nullptr,            WB, zc);
    mv_stage<true >(SC + (size_t)r * 32, SC + (size_t)iv*32, WC, zc);

    // MLP layer 1 (z -> relu h, staged back into same LDS column)
    float zr[CH];
    #pragma unroll
    for (int k = 0; k < CH; ++k) zr[k] = zc[k * 128];
    #pragma unroll 1
    for (int j0 = 0; j0 < CH; j0 += 8) {
        const float4 p0 = *(const float4*)(b1 + j0);
        const float4 p1 = *(const float4*)(b1 + j0 + 4);
        float acc[8] = {p0.x,p0.y,p0.z,p0.w,p1.x,p1.y,p1.z,p1.w};
        #pragma unroll
        for (int k = 0; k < CH; ++k) {
            const float* wr = W1 + k * CH + j0;
            #pragma unroll
            for (int jj = 0; jj < 8; ++jj)
                acc[jj] = fmaf(zr[k], wr[jj], acc[jj]);
        }
        #pragma unroll
        for (int jj = 0; jj < 8; ++jj)
            zc[(j0 + jj) * 128] = fmaxf(acc[jj], 0.0f);
    }

    // MLP layer 2
    float hr[CH];
    #pragma unroll
    for (int k = 0; k < CH; ++k) hr[k] = zc[k * 128];
    float* orow = out + (size_t)r * CH;
    #pragma unroll 1
    for (int j0 = 0; j0 < CH; j0 += 8) {
        const float4 p0 = *(const float4*)(b2 + j0);
        const float4 p1 = *(const float4*)(b2 + j0 + 4);
        float acc[8] = {p0.x,p0.y,p0.z,p0.w,p1.x,p1.y,p1.z,p1.w};
        #pragma unroll
        for (int k = 0; k < CH; ++k) {
            const float* wr = W2 + k * CH + j0;
            #pragma unroll
            for (int jj = 0; jj < 8; ++jj)
                acc[jj] = fmaf(hr[k], wr[jj], acc[jj]);
        }
        if (valid) {
            *(float4*)(orow + j0)     = make_float4(acc[0], acc[1], acc[2], acc[3]);
            *(float4*)(orow + j0 + 4) = make_float4(acc[4], acc[5], acc[6], acc[7]);
        }
    }
}

extern "C" void kernel_launch(void* const* d_in, const int* in_sizes, int n_in,
                              void* d_out, int out_size, void* d_ws, size_t ws_size,
                              hipStream_t stream)
{
    const float* ea  = (const float*)d_in[0];
    const float* ea2 = (const float*)d_in[1];
    const float* Wp  = (const float*)d_in[2];   // (6,64,64)
    const float* bp  = (const float*)d_in[3];   // (6,64)
    const float* W1a = (const float*)d_in[4];
    const float* b1a = (const float*)d_in[5];
    const float* W2a = (const float*)d_in[6];
    const float* b2a = (const float*)d_in[7];
    const float* W1b = (const float*)d_in[8];
    const float* b1b = (const float*)d_in[9];
    const float* W2b = (const float*)d_in[10];
    const float* b2b = (const float*)d_in[11];
    const int* t111 = (const int*)d_in[12];     // [3,T]: ij, ik, kj
    const int* t112 = (const int*)d_in[13];
    const int* t122 = (const int*)d_in[14];
    const int* t222 = (const int*)d_in[15];
    const int* inv1 = (const int*)d_in[16];
    const int* inv2 = (const int*)d_in[17];

    const int E    = in_sizes[0] / CH;
    const int E2   = in_sizes[1] / CH;
    const int T111 = in_sizes[12] / 3;
    const int T112 = in_sizes[13] / 3;
    const int T122 = in_sizes[14] / 3;
    const int T222 = in_sizes[15] / 3;

    float* out1 = (float*)d_out;
    float* out2 = out1 + (size_t)E * CH;

    const size_t R = (size_t)(E > E2 ? E : E2);   // rows per S buffer
    uint*  SA = (uint*)d_ws;          // R x 32 uints (bf16x2 per uint)
    uint*  SB = SA + R * 32;
    uint*  SC = SB + R * 32;
    float* cA = (float*)(SC + R * 32);
    float* cB = cA + R;
    float* cC = cB + R;

    const dim3 blk256(256), blk128(128);
    const int SCAT_NB = 4096;

    // ================= Phase 1 (edges1) =================
    hipMemsetAsync(SA, 0, (size_t)E * 128, stream);
    hipMemsetAsync(SB, 0, (size_t)E * 128, stream);
    hipMemsetAsync(SC, 0, (size_t)E * 128, stream);
    hipMemsetAsync(cA, 0, (size_t)E * 4, stream);
    hipMemsetAsync(cB, 0, (size_t)E * 4, stream);
    hipMemsetAsync(cC, 0, (size_t)E * 4, stream);

    // SA: ea[ik111]+ea[kj111] seg by ij111   (-> Wp0)
    scatter_sum_bf16<<<SCAT_NB, blk256, 0, stream>>>(
        ea, ea, t111 + 0, t111 + T111, t111 + 2 * T111, T111, SA, cA);
    // SB: ea2[ik122]+ea2[kj122] seg by ij122 (-> Wp2)
    scatter_sum_bf16<<<SCAT_NB, blk256, 0, stream>>>(
        ea2, ea2, t122 + 0, t122 + T122, t122 + 2 * T122, T122, SB, cB);
    // SC: ea[ik112]+ea2[kj112] seg by ij112  (-> Wp1, with inv1 doubling)
    scatter_sum_bf16<<<SCAT_NB, blk256, 0, stream>>>(
        ea, ea2, t112 + 0, t112 + T112, t112 + 2 * T112, T112, SC, cC);

    fused_finalize<<<(E + 127) / 128, blk128, 0, stream>>>(
        ea,
        SA, cA, Wp + 0 * CH * CH, bp + 0 * CH,
        SB, cB, Wp + 2 * CH * CH, bp + 2 * CH,
        SC, cC, Wp + 1 * CH * CH, bp + 1 * CH,
        inv1, W1a, b1a, W2a, b2a, E, out1);

    // ================= Phase 2 (edges2) =================
    hipMemsetAsync(SA, 0, (size_t)E2 * 128, stream);
    hipMemsetAsync(SB, 0, (size_t)E2 * 128, stream);
    hipMemsetAsync(SC, 0, (size_t)E2 * 128, stream);
    hipMemsetAsync(cA, 0, (size_t)E2 * 4, stream);
    hipMemsetAsync(cB, 0, (size_t)E2 * 4, stream);
    hipMemsetAsync(cC, 0, (size_t)E2 * 4, stream);

    // SA: out1[ij112]+out1[ik112] seg by kj112 (-> Wp3)
    scatter_sum_bf16<<<SCAT_NB, blk256, 0, stream>>>(
        out1, out1, t112 + 2 * T112, t112 + 0, t112 + T112, T112, SA, cA);
    // SB: ea2[ik222]+ea2[kj222] seg by ij222   (-> Wp5)
    scatter_sum_bf16<<<SCAT_NB, blk256, 0, stream>>>(
        ea2, ea2, t222 + 0, t222 + T222, t222 + 2 * T222, T222, SB, cB);
    // SC: out1[ij122]+ea2[kj122] seg by ik122   (-> Wp4, with inv2 doubling)
    scatter_sum_bf16<<<SCAT_NB, blk256, 0, stream>>>(
        out1, ea2, t122 + T122, t122 + 0, t122 + 2 * T122, T122, SC, cC);

    fused_finalize<<<(E2 + 127) / 128, blk128, 0, stream>>>(
        ea2,
        SA, cA, Wp + 3 * CH * CH, bp + 3 * CH,
        SB, cB, Wp + 5 * CH * CH, bp + 5 * CH,
        SC, cC, Wp + 4 * CH * CH, bp + 4 * CH,
        inv2, W1b, b1b, W2b, b2b, E2, out2);
}

// Round 4
// 1585.750 us; speedup vs baseline: 4.0068x; 1.5272x over previous
//
#include <hip/hip_runtime.h>

#define CH 64
typedef unsigned int uint;
typedef unsigned short ushort;

typedef __attribute__((ext_vector_type(8))) short bf16x8;
typedef __attribute__((ext_vector_type(4))) float f32x4;

// ---------- bf16 helpers ----------
__device__ __forceinline__ float bf_lo(uint u){ union{uint a;float f;}c; c.a=u<<16; return c.f; }
__device__ __forceinline__ float bf_hi(uint u){ union{uint a;float f;}c; c.a=u&0xffff0000u; return c.f; }
__device__ __forceinline__ ushort f2bf(float f){
    uint a = __float_as_uint(f);
    a = (a + 0x7fffu + ((a>>16)&1u)) >> 16;
    return (ushort)a;
}
__device__ __forceinline__ uint pack2(float lo, float hi){
    return (uint)f2bf(lo) | ((uint)f2bf(hi) << 16);
}
__device__ __forceinline__ void atom_pk(uint* addr, float lo, float hi){
    uint v = pack2(lo, hi);
    asm volatile("global_atomic_pk_add_bf16 %0, %1, off" :: "v"(addr), "v"(v) : "memory");
}

// ---------- scatter: S[dst] += bf16(A[ia]+B[ib]), cnt[dst] += 1 ----------
// 32 lanes per triangle (2 ch/lane), 2 triangles per wave. Sources fp32 or bf16.
template<bool ABF, bool BBF>
__global__ __launch_bounds__(256) void scatter_sum(
    const void* __restrict__ Av, const void* __restrict__ Bv,
    const int* __restrict__ idx_dst, const int* __restrict__ idx_a,
    const int* __restrict__ idx_b, int T,
    uint* __restrict__ S, float* __restrict__ cnt)
{
    const int l32  = threadIdx.x & 31;
    const int half = (threadIdx.x >> 5) & 1;
    const int wave  = blockIdx.x * (blockDim.x >> 6) + (threadIdx.x >> 6);
    const int nwave = gridDim.x * (blockDim.x >> 6);
    for (int w = wave; 2 * w < T; w += nwave) {
        const int t = 2 * w + half;
        if (t >= T) continue;
        const int ia = idx_a[t], ib = idx_b[t], id = idx_dst[t];
        float ax, ay, bx, by;
        if (ABF) { uint u = ((const uint*)Av)[(size_t)ia*32 + l32]; ax = bf_lo(u); ay = bf_hi(u); }
        else     { float2 v = ((const float2*)Av)[(size_t)ia*32 + l32]; ax = v.x; ay = v.y; }
        if (BBF) { uint u = ((const uint*)Bv)[(size_t)ib*32 + l32]; bx = bf_lo(u); by = bf_hi(u); }
        else     { float2 v = ((const float2*)Bv)[(size_t)ib*32 + l32]; bx = v.x; by = v.y; }
        atom_pk(S + (size_t)id*32 + l32, ax+bx, ay+by);
        if (l32 == 0) atomicAdd(&cnt[id], 1.0f);
    }
}

// ---------- fp32 -> packed bf16 row copies ----------
__global__ __launch_bounds__(256) void conv_bf16_kernel(
    const float* __restrict__ src, uint* __restrict__ dst, long n4)
{
    long i = (long)blockIdx.x * blockDim.x + threadIdx.x;
    const long stride = (long)gridDim.x * blockDim.x;
    for (; i < n4; i += stride) {
        const float4 v = ((const float4*)src)[i];
        uint2 o; o.x = pack2(v.x, v.y); o.y = pack2(v.z, v.w);
        ((uint2*)dst)[i] = o;
    }
}

// ---------- MFMA fused finalize ----------
// out[r] = mlp( base[r] + SA@WA + cA*bA + SB@WB + cB*bB
//               + (SC[r]+SC[inv])@WC + (cC[r]+cC[inv])*bC )
// Block = 256 thr = 4 waves, 64 rows/block (16 rows/wave).
// mfma_f32_16x16x32_bf16: A lane: row=l&15, k=8*(l>>4)+e (contiguous 8);
//                         B lane: col=l&15, k=8*(l>>4)+e;
//                         D lane: col=l&15, row=4*(l>>4)+reg   [m89-verified]
// Weights staged once per block in LDS as bf16 W^T [col][k], XOR-swizzled
// (byte ^= (col&7)<<4) so 16-row-strided ds_read_b128 is ~2-way (free).
__global__ __launch_bounds__(256) void fused_finalize_mfma(
    const float* __restrict__ base,
    const uint* __restrict__ SA, const float* __restrict__ cA,
    const float* __restrict__ WA, const float* __restrict__ bA,
    const uint* __restrict__ SB, const float* __restrict__ cB,
    const float* __restrict__ WB, const float* __restrict__ bB,
    const uint* __restrict__ SC, const float* __restrict__ cC,
    const float* __restrict__ WC, const float* __restrict__ bC,
    const int* __restrict__ inv,
    const float* __restrict__ W1, const float* __restrict__ b1,
    const float* __restrict__ W2, const float* __restrict__ b2,
    int N, float* __restrict__ out)
{
    __shared__ __attribute__((aligned(16))) char lds[49152]; // 5*8KB W + 4*2KB z
    const int tid = threadIdx.x;

    // ---- stage 5 weight matrices (fp32 [k][col] -> bf16 W^T, swizzled) ----
    const float* Wlist[5] = {WA, WB, WC, W1, W2};
    #pragma unroll
    for (int m = 0; m < 5; ++m) {
        const float* Wm = Wlist[m];
        for (int idx = tid; idx < 4096; idx += 256) {
            const int k = idx >> 6, col = idx & 63;       // coalesced global read
            *(ushort*)(lds + m*8192 + col*128 + ((2*k) ^ ((col&7)<<4))) = f2bf(Wm[idx]);
        }
    }
    __syncthreads();

    const int w = tid >> 6, lane = tid & 63;
    const int ln = lane & 15, grp = lane >> 4;
    const int r0 = blockIdx.x * 64 + w * 16;
    const int ra = (r0 + ln) < N ? (r0 + ln) : (N - 1);   // A-frag row (clamped)
    const int iva = inv[ra];
    char* zl = lds + 40960 + w * 2048;                    // per-wave 16x64 bf16

    auto ldS = [&](const uint* Srow, int kc) {
        union { uint4 u; bf16x8 h; } c;
        c.u = *(const uint4*)(Srow + kc*16 + grp*4);
        return c.h;
    };
    auto ldS2 = [&](const uint* r1, const uint* r2, int kc) {
        const uint4 a = *(const uint4*)(r1 + kc*16 + grp*4);
        const uint4 b = *(const uint4*)(r2 + kc*16 + grp*4);
        union { uint4 u; bf16x8 h; } c;
        c.u.x = pack2(bf_lo(a.x)+bf_lo(b.x), bf_hi(a.x)+bf_hi(b.x));
        c.u.y = pack2(bf_lo(a.y)+bf_lo(b.y), bf_hi(a.y)+bf_hi(b.y));
        c.u.z = pack2(bf_lo(a.z)+bf_lo(b.z), bf_hi(a.z)+bf_hi(b.z));
        c.u.w = pack2(bf_lo(a.w)+bf_lo(b.w), bf_hi(a.w)+bf_hi(b.w));
        return c.h;
    };
    auto ldW = [&](int m, int kc, int ct) {
        const int col = ct*16 + ln;
        const int k2  = (kc*32 + grp*8) * 2;
        return *(const bf16x8*)(lds + m*8192 + col*128 + (k2 ^ ((col&7)<<4)));
    };
    auto ldZ = [&](int kc) {
        const int k2 = (kc*32 + grp*8) * 2;
        return *(const bf16x8*)(zl + ln*128 + (k2 ^ ((ln&7)<<4)));
    };
    auto stZ = [&](int row, int col, float v) {
        *(ushort*)(zl + row*128 + ((2*col) ^ ((row&7)<<4))) = f2bf(v);
    };

    const uint* SArow  = SA + (size_t)ra * 32;
    const uint* SBrow  = SB + (size_t)ra * 32;
    const uint* SCrow  = SC + (size_t)ra * 32;
    const uint* SCrow2 = SC + (size_t)iva * 32;

    const f32x4 z4 = {0.f, 0.f, 0.f, 0.f};
    f32x4 acc[4] = {z4, z4, z4, z4};

    // ---- z = SA@WA + SB@WB + (SC+SCinv)@WC  (K=64 each, 2 chunks of 32) ----
    #pragma unroll
    for (int kc = 0; kc < 2; ++kc) {
        const bf16x8 aA = ldS(SArow, kc);
        const bf16x8 aB = ldS(SBrow, kc);
        const bf16x8 aC = ldS2(SCrow, SCrow2, kc);
        #pragma unroll
        for (int ct = 0; ct < 4; ++ct) {
            acc[ct] = __builtin_amdgcn_mfma_f32_16x16x32_bf16(aA, ldW(0,kc,ct), acc[ct], 0,0,0);
            acc[ct] = __builtin_amdgcn_mfma_f32_16x16x32_bf16(aB, ldW(1,kc,ct), acc[ct], 0,0,0);
            acc[ct] = __builtin_amdgcn_mfma_f32_16x16x32_bf16(aC, ldW(2,kc,ct), acc[ct], 0,0,0);
        }
    }

    // ---- fp32 epilogue: + base + counts*bias; write z to zl as bf16 ----
    #pragma unroll
    for (int reg = 0; reg < 4; ++reg) {
        const int rd = r0 + grp*4 + reg;
        const int rc = rd < N ? rd : (N - 1);
        const float fA = cA[rc], fB = cB[rc];
        const float fC = cC[rc] + cC[inv[rc]];
        #pragma unroll
        for (int ct = 0; ct < 4; ++ct) {
            const int col = ct*16 + ln;
            acc[ct][reg] += base[(size_t)rc*64 + col] + fA*bA[col] + fB*bB[col] + fC*bC[col];
        }
    }
    #pragma unroll
    for (int ct = 0; ct < 4; ++ct)
        #pragma unroll
        for (int reg = 0; reg < 4; ++reg)
            stZ(grp*4 + reg, ct*16 + ln, acc[ct][reg]);
    // zl is wave-private; DS ops within a wave are in-order -> no barrier.

    // ---- MLP layer 1: h = relu(z @ W1 + b1) ----
    f32x4 hacc[4] = {z4, z4, z4, z4};
    #pragma unroll
    for (int kc = 0; kc < 2; ++kc) {
        const bf16x8 az = ldZ(kc);
        #pragma unroll
        for (int ct = 0; ct < 4; ++ct)
            hacc[ct] = __builtin_amdgcn_mfma_f32_16x16x32_bf16(az, ldW(3,kc,ct), hacc[ct], 0,0,0);
    }
    #pragma unroll
    for (int ct = 0; ct < 4; ++ct)
        #pragma unroll
        for (int reg = 0; reg < 4; ++reg)
            stZ(grp*4 + reg, ct*16 + ln, fmaxf(hacc[ct][reg] + b1[ct*16 + ln], 0.f));

    // ---- MLP layer 2: out = h @ W2 + b2 ----
    f32x4 oacc[4] = {z4, z4, z4, z4};
    #pragma unroll
    for (int kc = 0; kc < 2; ++kc) {
        const bf16x8 ah = ldZ(kc);
        #pragma unroll
        for (int ct = 0; ct < 4; ++ct)
            oacc[ct] = __builtin_amdgcn_mfma_f32_16x16x32_bf16(ah, ldW(4,kc,ct), oacc[ct], 0,0,0);
    }
    #pragma unroll
    for (int reg = 0; reg < 4; ++reg) {
        const int rd = r0 + grp*4 + reg;
        if (rd < N) {
            #pragma unroll
            for (int ct = 0; ct < 4; ++ct) {
                const int col = ct*16 + ln;
                out[(size_t)rd*64 + col] = oacc[ct][reg] + b2[col];
            }
        }
    }
}

extern "C" void kernel_launch(void* const* d_in, const int* in_sizes, int n_in,
                              void* d_out, int out_size, void* d_ws, size_t ws_size,
                              hipStream_t stream)
{
    const float* ea  = (const float*)d_in[0];
    const float* ea2 = (const float*)d_in[1];
    const float* Wp  = (const float*)d_in[2];   // (6,64,64)
    const float* bp  = (const float*)d_in[3];   // (6,64)
    const float* W1a = (const float*)d_in[4];
    const float* b1a = (const float*)d_in[5];
    const float* W2a = (const float*)d_in[6];
    const float* b2a = (const float*)d_in[7];
    const float* W1b = (const float*)d_in[8];
    const float* b1b = (const float*)d_in[9];
    const float* W2b = (const float*)d_in[10];
    const float* b2b = (const float*)d_in[11];
    const int* t111 = (const int*)d_in[12];     // [3,T]: ij, ik, kj
    const int* t112 = (const int*)d_in[13];
    const int* t122 = (const int*)d_in[14];
    const int* t222 = (const int*)d_in[15];
    const int* inv1 = (const int*)d_in[16];
    const int* inv2 = (const int*)d_in[17];

    const int E    = in_sizes[0] / CH;
    const int E2   = in_sizes[1] / CH;
    const int T111 = in_sizes[12] / 3;
    const int T112 = in_sizes[13] / 3;
    const int T122 = in_sizes[14] / 3;
    const int T222 = in_sizes[15] / 3;

    float* out1 = (float*)d_out;
    float* out2 = out1 + (size_t)E * CH;

    const size_t R = (size_t)(E > E2 ? E : E2);
    char* p = (char*)d_ws;
    uint*  SA = (uint*)p;  p += R * 128;
    uint*  SB = (uint*)p;  p += R * 128;
    uint*  SC = (uint*)p;  p += R * 128;
    float* cA = (float*)p; p += R * 4;
    float* cB = (float*)p; p += R * 4;
    float* cC = (float*)p; p += R * 4;
    size_t used = (size_t)(p - (char*)d_ws);
    uint* ea2_bf = nullptr;
    uint* ea_bf  = nullptr;
    if (ws_size >= used + (size_t)E2 * 128) { ea2_bf = (uint*)p; p += (size_t)E2 * 128; used += (size_t)E2 * 128; }
    if (ws_size >= used + (size_t)E  * 128) { ea_bf  = (uint*)p; }

    const dim3 blk256(256);
    const int SCAT_NB = 4096;

    auto scat = [&](const void* A, bool abf, const void* B, bool bbf,
                    const int* dst, const int* ia, const int* ib, int T,
                    uint* S, float* c) {
        if (abf && bbf)
            scatter_sum<true, true ><<<SCAT_NB, blk256, 0, stream>>>(A, B, dst, ia, ib, T, S, c);
        else if (abf)
            scatter_sum<true, false><<<SCAT_NB, blk256, 0, stream>>>(A, B, dst, ia, ib, T, S, c);
        else if (bbf)
            scatter_sum<false, true><<<SCAT_NB, blk256, 0, stream>>>(A, B, dst, ia, ib, T, S, c);
        else
            scatter_sum<false, false><<<SCAT_NB, blk256, 0, stream>>>(A, B, dst, ia, ib, T, S, c);
    };

    if (ea2_bf) conv_bf16_kernel<<<2048, blk256, 0, stream>>>(ea2, ea2_bf, (long)E2 * 16);
    if (ea_bf)  conv_bf16_kernel<<<2048, blk256, 0, stream>>>(ea,  ea_bf,  (long)E  * 16);

    const void* eaS  = ea_bf  ? (const void*)ea_bf  : (const void*)ea;
    const void* ea2S = ea2_bf ? (const void*)ea2_bf : (const void*)ea2;
    const bool eaB = ea_bf != nullptr, ea2B = ea2_bf != nullptr;

    // ================= Phase 1 (edges1) =================
    hipMemsetAsync(SA, 0, (size_t)E * 128, stream);
    hipMemsetAsync(SB, 0, (size_t)E * 128, stream);
    hipMemsetAsync(SC, 0, (size_t)E * 128, stream);
    hipMemsetAsync(cA, 0, (size_t)E * 4, stream);
    hipMemsetAsync(cB, 0, (size_t)E * 4, stream);
    hipMemsetAsync(cC, 0, (size_t)E * 4, stream);

    // SA: ea[ik111]+ea[kj111] seg ij111   (-> Wp0)
    scat(eaS, eaB, eaS, eaB, t111 + 0, t111 + T111, t111 + 2*T111, T111, SA, cA);
    // SB: ea2[ik122]+ea2[kj122] seg ij122 (-> Wp2)
    scat(ea2S, ea2B, ea2S, ea2B, t122 + 0, t122 + T122, t122 + 2*T122, T122, SB, cB);
    // SC: ea[ik112]+ea2[kj112] seg ij112  (-> Wp1, doubled via inv1)
    scat(eaS, eaB, ea2S, ea2B, t112 + 0, t112 + T112, t112 + 2*T112, T112, SC, cC);

    fused_finalize_mfma<<<(E + 63) / 64, blk256, 0, stream>>>(
        ea,
        SA, cA, Wp + 0*CH*CH, bp + 0*CH,
        SB, cB, Wp + 2*CH*CH, bp + 2*CH,
        SC, cC, Wp + 1*CH*CH, bp + 1*CH,
        inv1, W1a, b1a, W2a, b2a, E, out1);

    // ================= Phase 2 (edges2) =================
    hipMemsetAsync(SA, 0, (size_t)E2 * 128, stream);
    hipMemsetAsync(SB, 0, (size_t)E2 * 128, stream);
    hipMemsetAsync(SC, 0, (size_t)E2 * 128, stream);
    hipMemsetAsync(cA, 0, (size_t)E2 * 4, stream);
    hipMemsetAsync(cB, 0, (size_t)E2 * 4, stream);
    hipMemsetAsync(cC, 0, (size_t)E2 * 4, stream);

    // SA: out1[ij112]+out1[ik112] seg kj112 (-> Wp3)
    scat(out1, false, out1, false, t112 + 2*T112, t112 + 0, t112 + T112, T112, SA, cA);
    // SB: ea2[ik222]+ea2[kj222] seg ij222   (-> Wp5)
    scat(ea2S, ea2B, ea2S, ea2B, t222 + 0, t222 + T222, t222 + 2*T222, T222, SB, cB);
    // SC: out1[ij122]+ea2[kj122] seg ik122   (-> Wp4, doubled via inv2)
    scat(out1, false, ea2S, ea2B, t122 + T122, t122 + 0, t122 + 2*T122, T122, SC, cC);

    fused_finalize_mfma<<<(E2 + 63) / 64, blk256, 0, stream>>>(
        ea2,
        SA, cA, Wp + 3*CH*CH, bp + 3*CH,
        SB, cB, Wp + 5*CH*CH, bp + 5*CH,
        SC, cC, Wp + 4*CH*CH, bp + 4*CH,
        inv2, W1b, b1b, W2b, b2b, E2, out2);
}